// Round 1
// baseline (2924.793 us; speedup 1.0000x reference)
//
#include <hip/hip_runtime.h>

__device__ __forceinline__ float leaky(float v){ return v > 0.f ? v : 0.1f*v; }

// efeat[e,j] = leaky( sum_k ea[e,k]*w1[k,j] + b1[j] ),  ea[e] = (x[dst]-x[src])[1:4]
__global__ void efeat_kernel(const float* __restrict__ x, const int* __restrict__ ei,
                             const float* __restrict__ w1, const float* __restrict__ b1,
                             float* __restrict__ out, int E){
  int id = blockIdx.x*256 + threadIdx.x;
  if (id >= E*64) return;
  int e = id >> 6, j = id & 63;
  int s = ei[e], d = ei[E+e];
  float a0 = x[d*4+1] - x[s*4+1];
  float a1 = x[d*4+2] - x[s*4+2];
  float a2 = x[d*4+3] - x[s*4+3];
  float v = a0*w1[j] + a1*w1[64+j] + a2*w1[128+j] + b1[j];
  out[id] = leaky(v);
}

// Layer 1 fused: W1 = leaky(ef1 @ w2 + b2) [E,4,8]; msg[o] = sum_i x[src,i]*W1[i,o]
__global__ void conv1_kernel(const float* __restrict__ ef, const float* __restrict__ x,
                             const int* __restrict__ ei, const float* __restrict__ w2,
                             const float* __restrict__ b2, float* __restrict__ agg, int E){
  int id = blockIdx.x*256 + threadIdx.x;
  if (id >= E*8) return;
  int e = id >> 3, o = id & 7;
  int s = ei[e], d = ei[E+e];
  const float* efe = ef + e*64;
  float z[4];
  #pragma unroll
  for (int i=0;i<4;i++) z[i] = b2[i*8+o];
  for (int k=0;k<64;k++){
    float a = efe[k];
    #pragma unroll
    for (int i=0;i<4;i++) z[i] += a*w2[k*32 + i*8 + o];
  }
  float msg = 0.f;
  #pragma unroll
  for (int i=0;i<4;i++) msg += x[s*4+i]*leaky(z[i]);
  atomicAdd(&agg[d*8+o], msg);
}

// node update: h = leaky(agg + hin @ root + cb), in-place on agg
template<int IC, int OC>
__global__ void node_kernel(float* __restrict__ h, const float* __restrict__ hin,
                            const float* __restrict__ root, const float* __restrict__ cb, int N){
  int id = blockIdx.x*256 + threadIdx.x;
  if (id >= N*OC) return;
  int n = id / OC, o = id % OC;
  float v = h[id] + cb[o];
  const float* hi = hin + n*IC;
  #pragma unroll
  for (int i=0;i<IC;i++) v += hi[i]*root[i*OC+o];
  h[id] = leaky(v);
}

// Layer 2 fused: block=256 (4 waves), each wave handles 4 edges; lane o in [0,64)
// msg[e,o] = sum_{i<8} h1[src,i] * leaky( dot64(ef2[e], w2[:, i*64+o]) + b2[i*64+o] )
__global__ void conv2_kernel(const float* __restrict__ ef, const float* __restrict__ h1,
                             const int* __restrict__ ei, const float* __restrict__ w2,
                             const float* __restrict__ b2, float* __restrict__ agg, int E){
  __shared__ float efs[16][64];
  __shared__ float hs[16][8];
  int tid = threadIdx.x;
  int eb = blockIdx.x*16;
  #pragma unroll
  for (int r=0;r<4;r++){
    int idx = tid + r*256;
    int le = idx >> 6, k = idx & 63;
    int e = eb + le;
    efs[le][k] = (e < E) ? ef[e*64 + k] : 0.f;
  }
  if (tid < 128){
    int le = tid >> 3, i = tid & 7;
    int e = eb + le;
    hs[le][i] = (e < E) ? h1[ei[e]*8 + i] : 0.f;
  }
  __syncthreads();
  int wv = tid >> 6, o = tid & 63;
  int le0 = wv*4;
  float msg[4] = {0.f,0.f,0.f,0.f};
  for (int i=0;i<8;i++){
    float z[4] = {0.f,0.f,0.f,0.f};
    const float* wc = w2 + i*64 + o;
    for (int k=0;k<64;k++){
      float w = wc[k*512];
      z[0] += efs[le0+0][k]*w;
      z[1] += efs[le0+1][k]*w;
      z[2] += efs[le0+2][k]*w;
      z[3] += efs[le0+3][k]*w;
    }
    float b = b2[i*64+o];
    #pragma unroll
    for (int j=0;j<4;j++) msg[j] += hs[le0+j][i]*leaky(z[j]+b);
  }
  #pragma unroll
  for (int j=0;j<4;j++){
    int e = eb + le0 + j;
    if (e < E) atomicAdd(&agg[ei[E+e]*64 + o], msg[j]);
  }
}

// Layer 3 fused (the 33.6 GF kernel): block=256, 32 edges x 128 cols, 4x4 reg tile.
// msg[e,o] = sum_{i<64} h2[src,i] * leaky( dot64(ef3[e], w2[:, i*128+o]) + b2[i*128+o] )
__global__ __launch_bounds__(256)
void conv3_kernel(const float* __restrict__ ef, const float* __restrict__ h2,
                  const int* __restrict__ ei, const float* __restrict__ w2,
                  const float* __restrict__ b2, float* __restrict__ agg, int E){
  __shared__ float efs[32][64];
  __shared__ float hs[32][64];
  int tid = threadIdx.x;
  int eb = blockIdx.x*32;
  #pragma unroll
  for (int r=0;r<8;r++){
    int idx = tid + r*256;
    int le = idx >> 6, k = idx & 63;
    int e = eb + le;
    if (e < E){
      efs[le][k] = ef[e*64 + k];
      hs[le][k]  = h2[ei[e]*64 + k];
    } else {
      efs[le][k] = 0.f; hs[le][k] = 0.f;
    }
  }
  __syncthreads();
  int og = tid & 31;   // o-group: cols o0..o0+3
  int eg = tid >> 5;   // e-group: edges e0..e0+3
  int o0 = og*4, e0 = eg*4;
  float msg[4][4] = {};
  const float4* w2v = reinterpret_cast<const float4*>(w2) + (o0 >> 2); // row stride 2048 f4
  const float4* b2v = reinterpret_cast<const float4*>(b2) + (o0 >> 2);
  for (int i=0;i<64;i++){
    float z[4][4] = {};
    const float4* wp = w2v + i*32;
    #pragma unroll 8
    for (int k=0;k<64;k++){
      float4 w = wp[k*2048];
      float a0 = efs[e0+0][k], a1 = efs[e0+1][k], a2 = efs[e0+2][k], a3 = efs[e0+3][k];
      z[0][0] += a0*w.x; z[0][1] += a0*w.y; z[0][2] += a0*w.z; z[0][3] += a0*w.w;
      z[1][0] += a1*w.x; z[1][1] += a1*w.y; z[1][2] += a1*w.z; z[1][3] += a1*w.w;
      z[2][0] += a2*w.x; z[2][1] += a2*w.y; z[2][2] += a2*w.z; z[2][3] += a2*w.w;
      z[3][0] += a3*w.x; z[3][1] += a3*w.y; z[3][2] += a3*w.z; z[3][3] += a3*w.w;
    }
    float4 b = b2v[i*32];
    #pragma unroll
    for (int j=0;j<4;j++){
      float hv = hs[e0+j][i];
      msg[j][0] += hv*leaky(z[j][0]+b.x);
      msg[j][1] += hv*leaky(z[j][1]+b.y);
      msg[j][2] += hv*leaky(z[j][2]+b.z);
      msg[j][3] += hv*leaky(z[j][3]+b.w);
    }
  }
  #pragma unroll
  for (int j=0;j<4;j++){
    int e = eb + e0 + j;
    if (e < E){
      int d = ei[E+e];
      float* ap = agg + d*128 + o0;
      atomicAdd(ap+0, msg[j][0]);
      atomicAdd(ap+1, msg[j][1]);
      atomicAdd(ap+2, msg[j][2]);
      atomicAdd(ap+3, msg[j][3]);
    }
  }
}

// sum-pool per graph: block=128 (channels), 64 contiguous nodes per block; batch sorted
__global__ void pool_kernel(const float* __restrict__ h3, const int* __restrict__ batch,
                            float* __restrict__ g, int N){
  int o = threadIdx.x;
  int n0 = blockIdx.x*64;
  if (n0 >= N) return;
  float acc = 0.f;
  int cur = batch[n0];
  for (int r=0;r<64;r++){
    int n = n0 + r;
    if (n >= N) break;
    int b = batch[n];
    if (b != cur){ atomicAdd(&g[cur*128+o], acc); acc = 0.f; cur = b; }
    acc += h3[n*128+o];
  }
  atomicAdd(&g[cur*128+o], acc);
}

// readout MLP: one block per graph
__global__ void head_kernel(const float* __restrict__ g,
                            const float* __restrict__ fc1w, const float* __restrict__ fc1b,
                            const float* __restrict__ fc2w, const float* __restrict__ fc2b,
                            const float* __restrict__ fc3w, const float* __restrict__ fc3b,
                            float* __restrict__ out){
  __shared__ float s1[128], s2[128];
  int gi = blockIdx.x, t = threadIdx.x;
  s1[t] = g[gi*128+t];
  __syncthreads();
  float v = fc1b[t];
  for (int i=0;i<128;i++) v += s1[i]*fc1w[i*128+t];
  s2[t] = leaky(v);
  __syncthreads();
  if (t < 64){
    float v2 = fc2b[t];
    for (int i=0;i<128;i++) v2 += s2[i]*fc2w[i*64+t];
    s1[t] = leaky(v2);
  }
  __syncthreads();
  if (t == 0){
    float v3 = fc3b[0];
    for (int i=0;i<64;i++) v3 += s1[i]*fc3w[i];
    out[gi] = v3;
  }
}

extern "C" void kernel_launch(void* const* d_in, const int* in_sizes, int n_in,
                              void* d_out, int out_size, void* d_ws, size_t ws_size,
                              hipStream_t stream) {
  const float* x      = (const float*)d_in[0];
  const int*   ei     = (const int*)  d_in[1];
  const int*   batch  = (const int*)  d_in[2];
  const float* en1_w1 = (const float*)d_in[3];  const float* en1_b1 = (const float*)d_in[4];
  const float* en1_w2 = (const float*)d_in[5];  const float* en1_b2 = (const float*)d_in[6];
  const float* en2_w1 = (const float*)d_in[7];  const float* en2_b1 = (const float*)d_in[8];
  const float* en2_w2 = (const float*)d_in[9];  const float* en2_b2 = (const float*)d_in[10];
  const float* en3_w1 = (const float*)d_in[11]; const float* en3_b1 = (const float*)d_in[12];
  const float* en3_w2 = (const float*)d_in[13]; const float* en3_b2 = (const float*)d_in[14];
  const float* root1  = (const float*)d_in[15]; const float* cb1    = (const float*)d_in[16];
  const float* root2  = (const float*)d_in[17]; const float* cb2    = (const float*)d_in[18];
  const float* root3  = (const float*)d_in[19]; const float* cb3    = (const float*)d_in[20];
  const float* fc1w   = (const float*)d_in[21]; const float* fc1b   = (const float*)d_in[22];
  const float* fc2w   = (const float*)d_in[23]; const float* fc2b   = (const float*)d_in[24];
  const float* fc3w   = (const float*)d_in[25]; const float* fc3b   = (const float*)d_in[26];
  float* out = (float*)d_out;

  const int N = in_sizes[0] / 4;
  const int E = in_sizes[1] / 2;
  const int G = 32;

  float* ws  = (float*)d_ws;
  float* ef1 = ws;
  float* ef2 = ef1 + (size_t)E*64;
  float* ef3 = ef2 + (size_t)E*64;
  float* a1  = ef3 + (size_t)E*64;          // [N,8]   agg1 -> h1 (in place)
  float* a2  = a1  + (size_t)N*8;           // [N,64]  agg2 -> h2
  float* a3  = a2  + (size_t)N*64;          // [N,128] agg3 -> h3
  float* g   = a3  + (size_t)N*128;         // [G,128]

  size_t zero_bytes = ((size_t)N*(8+64+128) + (size_t)G*128) * sizeof(float);
  hipMemsetAsync(a1, 0, zero_bytes, stream);

  int gE64 = (E*64 + 255)/256;
  efeat_kernel<<<gE64, 256, 0, stream>>>(x, ei, en1_w1, en1_b1, ef1, E);
  efeat_kernel<<<gE64, 256, 0, stream>>>(x, ei, en2_w1, en2_b1, ef2, E);
  efeat_kernel<<<gE64, 256, 0, stream>>>(x, ei, en3_w1, en3_b1, ef3, E);

  conv1_kernel<<<(E*8 + 255)/256, 256, 0, stream>>>(ef1, x, ei, en1_w2, en1_b2, a1, E);
  node_kernel<4,8><<<(N*8 + 255)/256, 256, 0, stream>>>(a1, x, root1, cb1, N);

  conv2_kernel<<<(E + 15)/16, 256, 0, stream>>>(ef2, a1, ei, en2_w2, en2_b2, a2, E);
  node_kernel<8,64><<<(N*64 + 255)/256, 256, 0, stream>>>(a2, a1, root2, cb2, N);

  conv3_kernel<<<(E + 31)/32, 256, 0, stream>>>(ef3, a2, ei, en3_w2, en3_b2, a3, E);
  node_kernel<64,128><<<(N*128 + 255)/256, 256, 0, stream>>>(a3, a2, root3, cb3, N);

  pool_kernel<<<(N + 63)/64, 128, 0, stream>>>(a3, batch, g, N);
  head_kernel<<<G, 128, 0, stream>>>(g, fc1w, fc1b, fc2w, fc2b, fc3w, fc3b, out);
}

// Round 2
// 915.705 us; speedup vs baseline: 3.1940x; 3.1940x over previous
//
#include <hip/hip_runtime.h>

__device__ __forceinline__ float leaky(float v){ return v > 0.f ? v : 0.1f*v; }

__device__ __forceinline__ void atomAdd(float* p, float v){
  unsafeAtomicAdd(p, v);   // native global_atomic_add_f32 on gfx950
}

// efeat[e,j] = leaky( sum_k ea[e,k]*w1[k,j] + b1[j] ),  ea[e] = (x[dst]-x[src])[1:4]
__global__ void efeat_kernel(const float* __restrict__ x, const int* __restrict__ ei,
                             const float* __restrict__ w1, const float* __restrict__ b1,
                             float* __restrict__ out, int E){
  int id = blockIdx.x*256 + threadIdx.x;
  if (id >= E*64) return;
  int e = id >> 6, j = id & 63;
  int s = ei[e], d = ei[E+e];
  float a0 = x[d*4+1] - x[s*4+1];
  float a1 = x[d*4+2] - x[s*4+2];
  float a2 = x[d*4+3] - x[s*4+3];
  float v = a0*w1[j] + a1*w1[64+j] + a2*w1[128+j] + b1[j];
  out[id] = leaky(v);
}

// Layer 1 fused: W1 = leaky(ef1 @ w2 + b2) [E,4,8]; msg[o] = sum_i x[src,i]*W1[i,o]
__global__ void conv1_kernel(const float* __restrict__ ef, const float* __restrict__ x,
                             const int* __restrict__ ei, const float* __restrict__ w2,
                             const float* __restrict__ b2, float* __restrict__ agg, int E){
  int id = blockIdx.x*256 + threadIdx.x;
  if (id >= E*8) return;
  int e = id >> 3, o = id & 7;
  int s = ei[e], d = ei[E+e];
  const float* efe = ef + e*64;
  float z[4];
  #pragma unroll
  for (int i=0;i<4;i++) z[i] = b2[i*8+o];
  for (int k=0;k<64;k++){
    float a = efe[k];
    #pragma unroll
    for (int i=0;i<4;i++) z[i] += a*w2[k*32 + i*8 + o];
  }
  float msg = 0.f;
  #pragma unroll
  for (int i=0;i<4;i++) msg += x[s*4+i]*leaky(z[i]);
  atomAdd(&agg[d*8+o], msg);
}

// node update: h = leaky(agg + hin @ root + cb), in-place on agg
template<int IC, int OC>
__global__ void node_kernel(float* __restrict__ h, const float* __restrict__ hin,
                            const float* __restrict__ root, const float* __restrict__ cb, int N){
  int id = blockIdx.x*256 + threadIdx.x;
  if (id >= N*OC) return;
  int n = id / OC, o = id % OC;
  float v = h[id] + cb[o];
  const float* hi = hin + n*IC;
  #pragma unroll
  for (int i=0;i<IC;i++) v += hi[i]*root[i*OC+o];
  h[id] = leaky(v);
}

// Layer 2 fused, conv3-style: block=256, 32 edges, thread tile 2 edges x 4 cols.
// w2 is [64 x 512]; per-edge W[i,o] at col i*64+o (i<8, o<64).
// msg[e,o] = sum_i h1[src,i] * leaky( dot64(ef2[e], w2[:, i*64+o]) + b2[i*64+o] )
__global__ __launch_bounds__(256)
void conv2_kernel(const float* __restrict__ ef, const float* __restrict__ h1,
                  const int* __restrict__ ei, const float* __restrict__ w2,
                  const float* __restrict__ b2, float* __restrict__ agg, int E){
  __shared__ float efs[32][64];
  __shared__ float hs[32][8];
  int tid = threadIdx.x;
  int eb = blockIdx.x*32;
  #pragma unroll
  for (int r=0;r<8;r++){
    int idx = tid + r*256;
    int le = idx >> 6, k = idx & 63;
    int e = eb + le;
    efs[le][k] = (e < E) ? ef[e*64 + k] : 0.f;
  }
  { // 32 edges x 8 in-ch = 256 loads
    int le = tid >> 3, i = tid & 7;
    int e = eb + le;
    hs[le][i] = (e < E) ? h1[ei[e]*8 + i] : 0.f;
  }
  __syncthreads();
  int og = tid & 15, eg = tid >> 4;   // o0 = og*4 in [0,64); edges e0 = eg*2
  int o0 = og*4, e0 = eg*2;
  float msg[2][4] = {};
  for (int i=0;i<8;i++){
    float z[2][4] = {};
    const float4* wp = reinterpret_cast<const float4*>(w2 + i*64 + o0); // k-stride = 128 f4
    #pragma unroll 8
    for (int k=0;k<64;k++){
      float4 w = wp[k*128];
      float a0 = efs[e0+0][k], a1 = efs[e0+1][k];
      z[0][0] += a0*w.x; z[0][1] += a0*w.y; z[0][2] += a0*w.z; z[0][3] += a0*w.w;
      z[1][0] += a1*w.x; z[1][1] += a1*w.y; z[1][2] += a1*w.z; z[1][3] += a1*w.w;
    }
    float4 b = *reinterpret_cast<const float4*>(b2 + i*64 + o0);
    #pragma unroll
    for (int j=0;j<2;j++){
      float hv = hs[e0+j][i];
      msg[j][0] += hv*leaky(z[j][0]+b.x);
      msg[j][1] += hv*leaky(z[j][1]+b.y);
      msg[j][2] += hv*leaky(z[j][2]+b.z);
      msg[j][3] += hv*leaky(z[j][3]+b.w);
    }
  }
  #pragma unroll
  for (int j=0;j<2;j++){
    int e = eb + e0 + j;
    if (e < E){
      int d = ei[E+e];
      float* ap = agg + d*64 + o0;
      atomAdd(ap+0, msg[j][0]);
      atomAdd(ap+1, msg[j][1]);
      atomAdd(ap+2, msg[j][2]);
      atomAdd(ap+3, msg[j][3]);
    }
  }
}

// Layer 3 fused (the 33.6 GF kernel): block=256, 32 edges x 128 cols, 4x4 reg tile.
// msg[e,o] = sum_{i<64} h2[src,i] * leaky( dot64(ef3[e], w2[:, i*128+o]) + b2[i*128+o] )
__global__ __launch_bounds__(256)
void conv3_kernel(const float* __restrict__ ef, const float* __restrict__ h2,
                  const int* __restrict__ ei, const float* __restrict__ w2,
                  const float* __restrict__ b2, float* __restrict__ agg, int E){
  __shared__ float efs[32][64];
  __shared__ float hs[32][64];
  int tid = threadIdx.x;
  int eb = blockIdx.x*32;
  #pragma unroll
  for (int r=0;r<8;r++){
    int idx = tid + r*256;
    int le = idx >> 6, k = idx & 63;
    int e = eb + le;
    if (e < E){
      efs[le][k] = ef[e*64 + k];
      hs[le][k]  = h2[ei[e]*64 + k];
    } else {
      efs[le][k] = 0.f; hs[le][k] = 0.f;
    }
  }
  __syncthreads();
  int og = tid & 31;   // o-group: cols o0..o0+3
  int eg = tid >> 5;   // e-group: edges e0..e0+3
  int o0 = og*4, e0 = eg*4;
  float msg[4][4] = {};
  const float4* w2v = reinterpret_cast<const float4*>(w2) + (o0 >> 2); // row stride 2048 f4
  const float4* b2v = reinterpret_cast<const float4*>(b2) + (o0 >> 2);
  for (int i=0;i<64;i++){
    float z[4][4] = {};
    const float4* wp = w2v + i*32;
    #pragma unroll 8
    for (int k=0;k<64;k++){
      float4 w = wp[k*2048];
      float a0 = efs[e0+0][k], a1 = efs[e0+1][k], a2 = efs[e0+2][k], a3 = efs[e0+3][k];
      z[0][0] += a0*w.x; z[0][1] += a0*w.y; z[0][2] += a0*w.z; z[0][3] += a0*w.w;
      z[1][0] += a1*w.x; z[1][1] += a1*w.y; z[1][2] += a1*w.z; z[1][3] += a1*w.w;
      z[2][0] += a2*w.x; z[2][1] += a2*w.y; z[2][2] += a2*w.z; z[2][3] += a2*w.w;
      z[3][0] += a3*w.x; z[3][1] += a3*w.y; z[3][2] += a3*w.z; z[3][3] += a3*w.w;
    }
    float4 b = b2v[i*32];
    #pragma unroll
    for (int j=0;j<4;j++){
      float hv = hs[e0+j][i];
      msg[j][0] += hv*leaky(z[j][0]+b.x);
      msg[j][1] += hv*leaky(z[j][1]+b.y);
      msg[j][2] += hv*leaky(z[j][2]+b.z);
      msg[j][3] += hv*leaky(z[j][3]+b.w);
    }
  }
  #pragma unroll
  for (int j=0;j<4;j++){
    int e = eb + e0 + j;
    if (e < E){
      int d = ei[E+e];
      float* ap = agg + d*128 + o0;
      atomAdd(ap+0, msg[j][0]);
      atomAdd(ap+1, msg[j][1]);
      atomAdd(ap+2, msg[j][2]);
      atomAdd(ap+3, msg[j][3]);
    }
  }
}

// sum-pool per graph: block=128 (channels), 64 contiguous nodes per block; batch sorted
__global__ void pool_kernel(const float* __restrict__ h3, const int* __restrict__ batch,
                            float* __restrict__ g, int N){
  int o = threadIdx.x;
  int n0 = blockIdx.x*64;
  if (n0 >= N) return;
  float acc = 0.f;
  int cur = batch[n0];
  for (int r=0;r<64;r++){
    int n = n0 + r;
    if (n >= N) break;
    int b = batch[n];
    if (b != cur){ atomAdd(&g[cur*128+o], acc); acc = 0.f; cur = b; }
    acc += h3[n*128+o];
  }
  atomAdd(&g[cur*128+o], acc);
}

// readout MLP: one block per graph
__global__ void head_kernel(const float* __restrict__ g,
                            const float* __restrict__ fc1w, const float* __restrict__ fc1b,
                            const float* __restrict__ fc2w, const float* __restrict__ fc2b,
                            const float* __restrict__ fc3w, const float* __restrict__ fc3b,
                            float* __restrict__ out){
  __shared__ float s1[128], s2[128];
  int gi = blockIdx.x, t = threadIdx.x;
  s1[t] = g[gi*128+t];
  __syncthreads();
  float v = fc1b[t];
  for (int i=0;i<128;i++) v += s1[i]*fc1w[i*128+t];
  s2[t] = leaky(v);
  __syncthreads();
  if (t < 64){
    float v2 = fc2b[t];
    for (int i=0;i<128;i++) v2 += s2[i]*fc2w[i*64+t];
    s1[t] = leaky(v2);
  }
  __syncthreads();
  if (t == 0){
    float v3 = fc3b[0];
    for (int i=0;i<64;i++) v3 += s1[i]*fc3w[i];
    out[gi] = v3;
  }
}

extern "C" void kernel_launch(void* const* d_in, const int* in_sizes, int n_in,
                              void* d_out, int out_size, void* d_ws, size_t ws_size,
                              hipStream_t stream) {
  const float* x      = (const float*)d_in[0];
  const int*   ei     = (const int*)  d_in[1];
  const int*   batch  = (const int*)  d_in[2];
  const float* en1_w1 = (const float*)d_in[3];  const float* en1_b1 = (const float*)d_in[4];
  const float* en1_w2 = (const float*)d_in[5];  const float* en1_b2 = (const float*)d_in[6];
  const float* en2_w1 = (const float*)d_in[7];  const float* en2_b1 = (const float*)d_in[8];
  const float* en2_w2 = (const float*)d_in[9];  const float* en2_b2 = (const float*)d_in[10];
  const float* en3_w1 = (const float*)d_in[11]; const float* en3_b1 = (const float*)d_in[12];
  const float* en3_w2 = (const float*)d_in[13]; const float* en3_b2 = (const float*)d_in[14];
  const float* root1  = (const float*)d_in[15]; const float* cb1    = (const float*)d_in[16];
  const float* root2  = (const float*)d_in[17]; const float* cb2    = (const float*)d_in[18];
  const float* root3  = (const float*)d_in[19]; const float* cb3    = (const float*)d_in[20];
  const float* fc1w   = (const float*)d_in[21]; const float* fc1b   = (const float*)d_in[22];
  const float* fc2w   = (const float*)d_in[23]; const float* fc2b   = (const float*)d_in[24];
  const float* fc3w   = (const float*)d_in[25]; const float* fc3b   = (const float*)d_in[26];
  float* out = (float*)d_out;

  const int N = in_sizes[0] / 4;
  const int E = in_sizes[1] / 2;
  const int G = 32;

  float* ws  = (float*)d_ws;
  float* ef1 = ws;
  float* ef2 = ef1 + (size_t)E*64;
  float* ef3 = ef2 + (size_t)E*64;
  float* a1  = ef3 + (size_t)E*64;          // [N,8]   agg1 -> h1 (in place)
  float* a2  = a1  + (size_t)N*8;           // [N,64]  agg2 -> h2
  float* a3  = a2  + (size_t)N*64;          // [N,128] agg3 -> h3
  float* g   = a3  + (size_t)N*128;         // [G,128]

  size_t zero_bytes = ((size_t)N*(8+64+128) + (size_t)G*128) * sizeof(float);
  hipMemsetAsync(a1, 0, zero_bytes, stream);

  int gE64 = (E*64 + 255)/256;
  efeat_kernel<<<gE64, 256, 0, stream>>>(x, ei, en1_w1, en1_b1, ef1, E);
  efeat_kernel<<<gE64, 256, 0, stream>>>(x, ei, en2_w1, en2_b1, ef2, E);
  efeat_kernel<<<gE64, 256, 0, stream>>>(x, ei, en3_w1, en3_b1, ef3, E);

  conv1_kernel<<<(E*8 + 255)/256, 256, 0, stream>>>(ef1, x, ei, en1_w2, en1_b2, a1, E);
  node_kernel<4,8><<<(N*8 + 255)/256, 256, 0, stream>>>(a1, x, root1, cb1, N);

  conv2_kernel<<<(E + 31)/32, 256, 0, stream>>>(ef2, a1, ei, en2_w2, en2_b2, a2, E);
  node_kernel<8,64><<<(N*64 + 255)/256, 256, 0, stream>>>(a2, a1, root2, cb2, N);

  conv3_kernel<<<(E + 31)/32, 256, 0, stream>>>(ef3, a2, ei, en3_w2, en3_b2, a3, E);
  node_kernel<64,128><<<(N*128 + 255)/256, 256, 0, stream>>>(a3, a2, root3, cb3, N);

  pool_kernel<<<(N + 63)/64, 128, 0, stream>>>(a3, batch, g, N);
  head_kernel<<<G, 128, 0, stream>>>(g, fc1w, fc1b, fc2w, fc2b, fc3w, fc3b, out);
}

// Round 3
// 261.429 us; speedup vs baseline: 11.1877x; 3.5027x over previous
//
#include <hip/hip_runtime.h>
#include <hip/hip_bf16.h>

typedef __attribute__((ext_vector_type(8))) short short8;
typedef __attribute__((ext_vector_type(4))) float floatx4;

__device__ __forceinline__ float leaky(float v){ return v > 0.f ? v : 0.1f*v; }
__device__ __forceinline__ void atomAdd(float* p, float v){ unsafeAtomicAdd(p, v); }
__device__ __forceinline__ short f2bf(float f){
  __hip_bfloat16 h = __float2bfloat16(f);
  return *reinterpret_cast<short*>(&h);
}

// Fused edge-feature kernel: all three edge nets' first layer in one pass.
// ef1 fp32 (for scalar conv1), ef2/ef3 bf16 (MFMA A operands). Pads rows [E,Epad) with 0.
__global__ void efeat_all(const float* __restrict__ x, const int* __restrict__ ei,
                          const float* __restrict__ w1a, const float* __restrict__ b1a,
                          const float* __restrict__ w1b, const float* __restrict__ b1b,
                          const float* __restrict__ w1c, const float* __restrict__ b1c,
                          float* __restrict__ ef1, short* __restrict__ ef2b,
                          short* __restrict__ ef3b, int E, int Epad){
  int id = blockIdx.x*256 + threadIdx.x;
  if (id >= Epad*64) return;
  int e = id >> 6, j = id & 63;
  if (e >= E){ ef1[id] = 0.f; ef2b[id] = 0; ef3b[id] = 0; return; }
  int s = ei[e], d = ei[E+e];
  float a0 = x[d*4+1] - x[s*4+1];
  float a1 = x[d*4+2] - x[s*4+2];
  float a2 = x[d*4+3] - x[s*4+3];
  float v1 = leaky(a0*w1a[j] + a1*w1a[64+j] + a2*w1a[128+j] + b1a[j]);
  float v2 = leaky(a0*w1b[j] + a1*w1b[64+j] + a2*w1b[128+j] + b1b[j]);
  float v3 = leaky(a0*w1c[j] + a1*w1c[64+j] + a2*w1c[128+j] + b1c[j]);
  ef1[id] = v1;
  ef2b[id] = f2bf(v2);
  ef3b[id] = f2bf(v3);
}

// Pack w2 [64 x IC*OC] f32 into bf16 MFMA B-fragment order.
// chunk c = (i*OT + otg)*2 + kh ; within chunk: lane*8 elems, elem j -> B[k=kh*32+q*8+j][col=i*OC+otg*16+n]
template<int IC, int OC>
__global__ void pack_w2(const float* __restrict__ w2, short* __restrict__ w2p){
  constexpr int OT = OC/16;
  int tid = blockIdx.x*256 + threadIdx.x;
  int lane = tid & 63;
  int c = tid >> 6;
  if (c >= IC*OT*2) return;
  int kh = c & 1;
  int rem = c >> 1;
  int otg = rem % OT;
  int i = rem / OT;
  int n = lane & 15, q = lane >> 4;
  short out[8];
  #pragma unroll
  for (int j=0;j<8;j++){
    int k = kh*32 + q*8 + j;
    out[j] = f2bf(w2[(size_t)k*(IC*OC) + i*OC + otg*16 + n]);
  }
  *reinterpret_cast<short8*>(w2p + (size_t)c*512 + lane*8) = *reinterpret_cast<short8*>(out);
}

// Layer 1 fused (tiny: 131 MF): scalar path on fp32 ef1.
__global__ void conv1_kernel(const float* __restrict__ ef, const float* __restrict__ x,
                             const int* __restrict__ ei, const float* __restrict__ w2,
                             const float* __restrict__ b2, float* __restrict__ agg, int E){
  int id = blockIdx.x*256 + threadIdx.x;
  if (id >= E*8) return;
  int e = id >> 3, o = id & 7;
  int s = ei[e], d = ei[E+e];
  const float* efe = ef + (size_t)e*64;
  float z[4];
  #pragma unroll
  for (int i=0;i<4;i++) z[i] = b2[i*8+o];
  for (int k=0;k<64;k++){
    float a = efe[k];
    #pragma unroll
    for (int i=0;i<4;i++) z[i] += a*w2[k*32 + i*8 + o];
  }
  float msg = 0.f;
  #pragma unroll
  for (int i=0;i<4;i++) msg += x[s*4+i]*leaky(z[i]);
  atomAdd(&agg[d*8+o], msg);
}

// node update: h = leaky(agg + hin @ root + cb), in-place on agg
template<int IC, int OC>
__global__ void node_kernel(float* __restrict__ h, const float* __restrict__ hin,
                            const float* __restrict__ root, const float* __restrict__ cb, int N){
  int id = blockIdx.x*256 + threadIdx.x;
  if (id >= N*OC) return;
  int n = id / OC, o = id % OC;
  float v = h[id] + cb[o];
  const float* hi = hin + (size_t)n*IC;
  #pragma unroll
  for (int i=0;i<IC;i++) v += hi[i]*root[i*OC+o];
  h[id] = leaky(v);
}

// MFMA NNConv: 64 edges/block, 4 waves each owning OC/4 output cols across all IC.
// z[e, i*OC+o] = bias + dot64(ef[e], w2col) via 2x mfma_16x16x32_bf16;
// msg[e,o] += h[src_e, i] * leaky(z)  (fp32 epilogue); atomic scatter to agg.
template<int IC, int OC>
__global__ __launch_bounds__(256)
void conv_mfma(const short* __restrict__ efb, const float* __restrict__ h,
               const int* __restrict__ ei, const short* __restrict__ w2p,
               const float* __restrict__ b2, float* __restrict__ agg,
               int E, int Epad){
  constexpr int OT  = OC/16;   // o-tiles total
  constexpr int WOT = OT/4;    // o-tiles per wave
  __shared__ float hsT[IC][64];
  __shared__ int sdst[64];
  int tid = threadIdx.x;
  int eb = blockIdx.x*64;

  { // load h transposed into LDS: hsT[i][e]
    int e = tid & 63;
    int ge = eb + e;
    bool valid = ge < E;
    int src = valid ? ei[ge] : 0;
    if constexpr (IC == 64){
      int i0 = (tid >> 6) * 16;
      const float4* hp = reinterpret_cast<const float4*>(h + (size_t)src*64 + i0);
      #pragma unroll
      for (int r=0;r<4;r++){
        float4 hv = valid ? hp[r] : float4{0.f,0.f,0.f,0.f};
        hsT[i0 + r*4 + 0][e] = hv.x;
        hsT[i0 + r*4 + 1][e] = hv.y;
        hsT[i0 + r*4 + 2][e] = hv.z;
        hsT[i0 + r*4 + 3][e] = hv.w;
      }
    } else { // IC == 8
      int i0 = (tid >> 6) * 2;
      float2 hv = valid ? *reinterpret_cast<const float2*>(h + (size_t)src*8 + i0)
                        : float2{0.f,0.f};
      hsT[i0 + 0][e] = hv.x;
      hsT[i0 + 1][e] = hv.y;
    }
    if (tid < 64) sdst[tid] = (eb + tid < E) ? ei[E + eb + tid] : -1;
  }
  __syncthreads();

  int lane = tid & 63;
  int wv = tid >> 6;
  int n = lane & 15, quad = lane >> 4;
  int o0 = wv * (OC/4);

  // Persistent A fragments: 4 m-tiles x 2 k-halves (K total = 64)
  short8 A[4][2];
  #pragma unroll
  for (int m=0;m<4;m++)
    #pragma unroll
    for (int kh=0;kh<2;kh++)
      A[m][kh] = *reinterpret_cast<const short8*>(efb + (size_t)(eb + m*16 + n)*64 + kh*32 + quad*8);

  float msg[4][WOT][4];
  #pragma unroll
  for (int m=0;m<4;m++)
    #pragma unroll
    for (int t=0;t<WOT;t++)
      #pragma unroll
      for (int r=0;r<4;r++) msg[m][t][r] = 0.f;

  for (int i=0;i<IC;i++){
    short8 B[WOT][2];
    float bz[WOT];
    #pragma unroll
    for (int t=0;t<WOT;t++){
      int otg = (o0 >> 4) + t;
      #pragma unroll
      for (int kh=0;kh<2;kh++)
        B[t][kh] = *reinterpret_cast<const short8*>(w2p + ((size_t)((i*OT + otg)*2 + kh) << 9) + lane*8);
      bz[t] = b2[i*OC + o0 + t*16 + n];
    }
    #pragma unroll
    for (int m=0;m<4;m++){
      float4 hv = *reinterpret_cast<const float4*>(&hsT[i][m*16 + quad*4]);
      #pragma unroll
      for (int t=0;t<WOT;t++){
        floatx4 z = {bz[t], bz[t], bz[t], bz[t]};
        z = __builtin_amdgcn_mfma_f32_16x16x32_bf16(A[m][0], B[t][0], z, 0, 0, 0);
        z = __builtin_amdgcn_mfma_f32_16x16x32_bf16(A[m][1], B[t][1], z, 0, 0, 0);
        float l0 = fmaxf(z[0], 0.1f*z[0]);
        float l1 = fmaxf(z[1], 0.1f*z[1]);
        float l2 = fmaxf(z[2], 0.1f*z[2]);
        float l3 = fmaxf(z[3], 0.1f*z[3]);
        msg[m][t][0] += hv.x*l0;
        msg[m][t][1] += hv.y*l1;
        msg[m][t][2] += hv.z*l2;
        msg[m][t][3] += hv.w*l3;
      }
    }
  }

  #pragma unroll
  for (int m=0;m<4;m++){
    #pragma unroll
    for (int r=0;r<4;r++){
      int d = sdst[m*16 + quad*4 + r];
      if (d >= 0){
        #pragma unroll
        for (int t=0;t<WOT;t++)
          atomAdd(&agg[(size_t)d*OC + o0 + t*16 + n], msg[m][t][r]);
      }
    }
  }
}

// sum-pool per graph: block=128 (channels), 64 contiguous nodes per block; batch sorted
__global__ void pool_kernel(const float* __restrict__ h3, const int* __restrict__ batch,
                            float* __restrict__ g, int N){
  int o = threadIdx.x;
  int n0 = blockIdx.x*64;
  if (n0 >= N) return;
  float acc = 0.f;
  int cur = batch[n0];
  for (int r=0;r<64;r++){
    int n = n0 + r;
    if (n >= N) break;
    int b = batch[n];
    if (b != cur){ atomAdd(&g[cur*128+o], acc); acc = 0.f; cur = b; }
    acc += h3[(size_t)n*128+o];
  }
  atomAdd(&g[cur*128+o], acc);
}

// readout MLP: one block per graph
__global__ void head_kernel(const float* __restrict__ g,
                            const float* __restrict__ fc1w, const float* __restrict__ fc1b,
                            const float* __restrict__ fc2w, const float* __restrict__ fc2b,
                            const float* __restrict__ fc3w, const float* __restrict__ fc3b,
                            float* __restrict__ out){
  __shared__ float s1[128], s2[128];
  int gi = blockIdx.x, t = threadIdx.x;
  s1[t] = g[gi*128+t];
  __syncthreads();
  float v = fc1b[t];
  for (int i=0;i<128;i++) v += s1[i]*fc1w[i*128+t];
  s2[t] = leaky(v);
  __syncthreads();
  if (t < 64){
    float v2 = fc2b[t];
    for (int i=0;i<128;i++) v2 += s2[i]*fc2w[i*64+t];
    s1[t] = leaky(v2);
  }
  __syncthreads();
  if (t == 0){
    float v3 = fc3b[0];
    for (int i=0;i<64;i++) v3 += s1[i]*fc3w[i];
    out[gi] = v3;
  }
}

extern "C" void kernel_launch(void* const* d_in, const int* in_sizes, int n_in,
                              void* d_out, int out_size, void* d_ws, size_t ws_size,
                              hipStream_t stream) {
  const float* x      = (const float*)d_in[0];
  const int*   ei     = (const int*)  d_in[1];
  const int*   batch  = (const int*)  d_in[2];
  const float* en1_w1 = (const float*)d_in[3];  const float* en1_b1 = (const float*)d_in[4];
  const float* en1_w2 = (const float*)d_in[5];  const float* en1_b2 = (const float*)d_in[6];
  const float* en2_w1 = (const float*)d_in[7];  const float* en2_b1 = (const float*)d_in[8];
  const float* en2_w2 = (const float*)d_in[9];  const float* en2_b2 = (const float*)d_in[10];
  const float* en3_w1 = (const float*)d_in[11]; const float* en3_b1 = (const float*)d_in[12];
  const float* en3_w2 = (const float*)d_in[13]; const float* en3_b2 = (const float*)d_in[14];
  const float* root1  = (const float*)d_in[15]; const float* cb1    = (const float*)d_in[16];
  const float* root2  = (const float*)d_in[17]; const float* cb2    = (const float*)d_in[18];
  const float* root3  = (const float*)d_in[19]; const float* cb3    = (const float*)d_in[20];
  const float* fc1w   = (const float*)d_in[21]; const float* fc1b   = (const float*)d_in[22];
  const float* fc2w   = (const float*)d_in[23]; const float* fc2b   = (const float*)d_in[24];
  const float* fc3w   = (const float*)d_in[25]; const float* fc3b   = (const float*)d_in[26];
  float* out = (float*)d_out;

  const int N = in_sizes[0] / 4;
  const int E = in_sizes[1] / 2;
  const int G = 32;
  const int Epad = (E + 63) & ~63;

  float* ef1  = (float*)d_ws;
  short* ef2b = (short*)(ef1 + (size_t)Epad*64);
  short* ef3b = ef2b + (size_t)Epad*64;
  short* w2p2 = ef3b + (size_t)Epad*64;
  short* w2p3 = w2p2 + 8*4*2*512;          // 32768 shorts
  float* a1   = (float*)(w2p3 + 64*8*2*512); // 524288 shorts
  float* a2   = a1 + (size_t)N*8;
  float* a3   = a2 + (size_t)N*64;
  float* g    = a3 + (size_t)N*128;

  size_t zero_bytes = ((size_t)N*(8+64+128) + (size_t)G*128) * sizeof(float);
  hipMemsetAsync(a1, 0, zero_bytes, stream);

  efeat_all<<<(Epad*64 + 255)/256, 256, 0, stream>>>(
      x, ei, en1_w1, en1_b1, en2_w1, en2_b1, en3_w1, en3_b1,
      ef1, ef2b, ef3b, E, Epad);

  pack_w2<8,64><<<(8*4*2*64 + 255)/256, 256, 0, stream>>>(en2_w2, w2p2);
  pack_w2<64,128><<<(64*8*2*64 + 255)/256, 256, 0, stream>>>(en3_w2, w2p3);

  conv1_kernel<<<(E*8 + 255)/256, 256, 0, stream>>>(ef1, x, ei, en1_w2, en1_b2, a1, E);
  node_kernel<4,8><<<(N*8 + 255)/256, 256, 0, stream>>>(a1, x, root1, cb1, N);

  conv_mfma<8,64><<<Epad/64, 256, 0, stream>>>(ef2b, a1, ei, w2p2, en2_b2, a2, E, Epad);
  node_kernel<8,64><<<(N*64 + 255)/256, 256, 0, stream>>>(a2, a1, root2, cb2, N);

  conv_mfma<64,128><<<Epad/64, 256, 0, stream>>>(ef3b, a2, ei, w2p3, en3_b2, a3, E, Epad);
  node_kernel<64,128><<<(N*128 + 255)/256, 256, 0, stream>>>(a3, a2, root3, cb3, N);

  pool_kernel<<<(N + 63)/64, 128, 0, stream>>>(a3, batch, g, N);
  head_kernel<<<G, 128, 0, stream>>>(g, fc1w, fc1b, fc2w, fc2b, fc3w, fc3b, out);
}

// Round 4
// 254.116 us; speedup vs baseline: 11.5097x; 1.0288x over previous
//
#include <hip/hip_runtime.h>
#include <hip/hip_bf16.h>

typedef __attribute__((ext_vector_type(8))) short short8;
typedef __attribute__((ext_vector_type(4))) float floatx4;

__device__ __forceinline__ float leaky(float v){ return v > 0.f ? v : 0.1f*v; }
__device__ __forceinline__ void atomAdd(float* p, float v){ unsafeAtomicAdd(p, v); }
__device__ __forceinline__ short f2bf(float f){
  __hip_bfloat16 h = __float2bfloat16(f);
  return *reinterpret_cast<short*>(&h);
}

// Fused edge-feature kernel: all three edge nets' first layer in one pass.
__global__ void efeat_all(const float* __restrict__ x, const int* __restrict__ ei,
                          const float* __restrict__ w1a, const float* __restrict__ b1a,
                          const float* __restrict__ w1b, const float* __restrict__ b1b,
                          const float* __restrict__ w1c, const float* __restrict__ b1c,
                          float* __restrict__ ef1, short* __restrict__ ef2b,
                          short* __restrict__ ef3b, int E, int Epad){
  int id = blockIdx.x*256 + threadIdx.x;
  if (id >= Epad*64) return;
  int e = id >> 6, j = id & 63;
  if (e >= E){ ef1[id] = 0.f; ef2b[id] = 0; ef3b[id] = 0; return; }
  int s = ei[e], d = ei[E+e];
  float a0 = x[d*4+1] - x[s*4+1];
  float a1 = x[d*4+2] - x[s*4+2];
  float a2 = x[d*4+3] - x[s*4+3];
  float v1 = leaky(a0*w1a[j] + a1*w1a[64+j] + a2*w1a[128+j] + b1a[j]);
  float v2 = leaky(a0*w1b[j] + a1*w1b[64+j] + a2*w1b[128+j] + b1b[j]);
  float v3 = leaky(a0*w1c[j] + a1*w1c[64+j] + a2*w1c[128+j] + b1c[j]);
  ef1[id] = v1;
  ef2b[id] = f2bf(v2);
  ef3b[id] = f2bf(v3);
}

// Pack BOTH w2 matrices into bf16 MFMA B-fragment order in one dispatch.
// chunk c = (i*OT + otg)*2 + kh ; elem j of lane -> B[k=kh*32+q*8+j][col=i*OC+otg*16+n]
__global__ void pack_w2_all(const float* __restrict__ w2a, short* __restrict__ pa,
                            const float* __restrict__ w2b, short* __restrict__ pb){
  int bid = blockIdx.x;
  const float* w2; short* dst; int IC, OC, cbase;
  if (bid < 16){ w2 = w2a; dst = pa; IC = 8;  OC = 64;  cbase = bid*4; }        // 64 chunks
  else        { w2 = w2b; dst = pb; IC = 64; OC = 128; cbase = (bid-16)*4; }    // 1024 chunks
  int lane = threadIdx.x & 63;
  int c = cbase + (threadIdx.x >> 6);
  int OT = OC/16;
  int kh = c & 1; int rem = c >> 1; int otg = rem % OT; int i = rem / OT;
  int n = lane & 15, q = lane >> 4;
  short out[8];
  #pragma unroll
  for (int j=0;j<8;j++){
    int k = kh*32 + q*8 + j;
    out[j] = f2bf(w2[(size_t)k*(IC*OC) + i*OC + otg*16 + n]);
  }
  *reinterpret_cast<short8*>(dst + (size_t)c*512 + lane*8) = *reinterpret_cast<short8*>(out);
}

// Layer 1 (tiny: 131 MF): scalar path on fp32 ef1.
__global__ void conv1_kernel(const float* __restrict__ ef, const float* __restrict__ x,
                             const int* __restrict__ ei, const float* __restrict__ w2,
                             const float* __restrict__ b2, float* __restrict__ agg, int E){
  int id = blockIdx.x*256 + threadIdx.x;
  if (id >= E*8) return;
  int e = id >> 3, o = id & 7;
  int s = ei[e], d = ei[E+e];
  const float* efe = ef + (size_t)e*64;
  float z[4];
  #pragma unroll
  for (int i=0;i<4;i++) z[i] = b2[i*8+o];
  for (int k=0;k<64;k++){
    float a = efe[k];
    #pragma unroll
    for (int i=0;i<4;i++) z[i] += a*w2[k*32 + i*8 + o];
  }
  float msg = 0.f;
  #pragma unroll
  for (int i=0;i<4;i++) msg += x[s*4+i]*leaky(z[i]);
  atomAdd(&agg[d*8+o], msg);
}

// node update: h = leaky(agg + hin @ root + cb), in-place on agg
template<int IC, int OC>
__global__ void node_kernel(float* __restrict__ h, const float* __restrict__ hin,
                            const float* __restrict__ root, const float* __restrict__ cb, int N){
  int id = blockIdx.x*256 + threadIdx.x;
  if (id >= N*OC) return;
  int n = id / OC, o = id % OC;
  float v = h[id] + cb[o];
  const float* hi = hin + (size_t)n*IC;
  #pragma unroll
  for (int i=0;i<IC;i++) v += hi[i]*root[i*OC+o];
  h[id] = leaky(v);
}

// node3 + pool fused: v = leaky(agg3[n] + h2[n]@root + cb); g[batch[n]] += v. h3 never stored.
__global__ void node3_pool(const float* __restrict__ agg, const float* __restrict__ hin,
                           const float* __restrict__ root, const float* __restrict__ cb,
                           const int* __restrict__ batch, float* __restrict__ g, int N){
  int id = blockIdx.x*256 + threadIdx.x;
  if (id >= N*128) return;
  int n = id >> 7, o = id & 127;
  float v = agg[id] + cb[o];
  const float* hi = hin + (size_t)n*64;
  #pragma unroll
  for (int i=0;i<64;i++) v += hi[i]*root[i*128+o];
  atomAdd(&g[batch[n]*128 + o], leaky(v));
}

// Generalized MFMA NNConv.
//  MB  = 16-edge m-tiles per block (edges/block = MB*16)
//  ICB = input channels handled per block (IC/ICB blocks cooperate via atomics)
// Grid: (Epad/(MB*16)) * (IC/ICB) blocks of 256.
template<int IC, int OC, int MB, int ICB>
__global__ __launch_bounds__(256)
void conv_mfma(const short* __restrict__ efb, const float* __restrict__ h,
               const int* __restrict__ ei, const short* __restrict__ w2p,
               const float* __restrict__ b2, float* __restrict__ agg, int E){
  constexpr int ME   = MB*16;     // edges per block
  constexpr int OT   = OC/16;     // o-tiles total
  constexpr int WOT  = OT/4;      // o-tiles per wave
  constexpr int NSPL = IC/ICB;    // ic-split factor
  __shared__ float hsT[ICB][ME];
  __shared__ int sdst[ME];
  int tid = threadIdx.x;
  int bi = blockIdx.x;
  int eb = (bi / NSPL) * ME;
  int i0 = (bi % NSPL) * ICB;

  { // stage h[src, i0:i0+ICB] transposed into hsT[i_local][e]
    int e = tid % ME;
    int ge = eb + e;
    bool valid = ge < E;
    int src = valid ? ei[ge] : 0;
    constexpr int CH  = 256/ME;        // thread-groups along i
    constexpr int IPC = ICB/CH;        // i's per thread
    int c = tid / ME;
    const float* hp = h + (size_t)src*IC + i0 + c*IPC;
    if constexpr (IPC == 8){
      #pragma unroll
      for (int half=0; half<2; half++){
        float4 hv = valid ? reinterpret_cast<const float4*>(hp)[half]
                          : float4{0.f,0.f,0.f,0.f};
        hsT[c*IPC + half*4 + 0][e] = hv.x;
        hsT[c*IPC + half*4 + 1][e] = hv.y;
        hsT[c*IPC + half*4 + 2][e] = hv.z;
        hsT[c*IPC + half*4 + 3][e] = hv.w;
      }
    } else {
      #pragma unroll
      for (int j=0;j<IPC;j++)
        hsT[c*IPC + j][e] = valid ? hp[j] : 0.f;
    }
    if (tid < ME) sdst[tid] = (eb + tid < E) ? ei[E + eb + tid] : -1;
  }
  __syncthreads();

  int lane = tid & 63;
  int wv = tid >> 6;
  int n = lane & 15, quad = lane >> 4;
  int o0 = wv * (OC/4);

  // Persistent A fragments (full K=64 ef-dim contraction)
  short8 A[MB][2];
  #pragma unroll
  for (int m=0;m<MB;m++)
    #pragma unroll
    for (int kh=0;kh<2;kh++)
      A[m][kh] = *reinterpret_cast<const short8*>(efb + (size_t)(eb + m*16 + n)*64 + kh*32 + quad*8);

  float msg[MB][WOT][4];
  #pragma unroll
  for (int m=0;m<MB;m++)
    #pragma unroll
    for (int t=0;t<WOT;t++)
      #pragma unroll
      for (int r=0;r<4;r++) msg[m][t][r] = 0.f;

  for (int i=0;i<ICB;i++){
    int ig = i0 + i;
    short8 B[WOT][2];
    float bz[WOT];
    #pragma unroll
    for (int t=0;t<WOT;t++){
      int otg = (o0 >> 4) + t;
      #pragma unroll
      for (int kh=0;kh<2;kh++)
        B[t][kh] = *reinterpret_cast<const short8*>(w2p + ((size_t)((ig*OT + otg)*2 + kh) << 9) + lane*8);
      bz[t] = b2[ig*OC + o0 + t*16 + n];
    }
    #pragma unroll
    for (int m=0;m<MB;m++){
      float4 hv = *reinterpret_cast<const float4*>(&hsT[i][m*16 + quad*4]);
      #pragma unroll
      for (int t=0;t<WOT;t++){
        floatx4 z = {bz[t], bz[t], bz[t], bz[t]};
        z = __builtin_amdgcn_mfma_f32_16x16x32_bf16(A[m][0], B[t][0], z, 0, 0, 0);
        z = __builtin_amdgcn_mfma_f32_16x16x32_bf16(A[m][1], B[t][1], z, 0, 0, 0);
        float l0 = fmaxf(z[0], 0.1f*z[0]);
        float l1 = fmaxf(z[1], 0.1f*z[1]);
        float l2 = fmaxf(z[2], 0.1f*z[2]);
        float l3 = fmaxf(z[3], 0.1f*z[3]);
        msg[m][t][0] += hv.x*l0;
        msg[m][t][1] += hv.y*l1;
        msg[m][t][2] += hv.z*l2;
        msg[m][t][3] += hv.w*l3;
      }
    }
  }

  #pragma unroll
  for (int m=0;m<MB;m++){
    #pragma unroll
    for (int r=0;r<4;r++){
      int d = sdst[m*16 + quad*4 + r];
      if (d >= 0){
        #pragma unroll
        for (int t=0;t<WOT;t++)
          atomAdd(&agg[(size_t)d*OC + o0 + t*16 + n], msg[m][t][r]);
      }
    }
  }
}

// readout MLP: one block per graph
__global__ void head_kernel(const float* __restrict__ g,
                            const float* __restrict__ fc1w, const float* __restrict__ fc1b,
                            const float* __restrict__ fc2w, const float* __restrict__ fc2b,
                            const float* __restrict__ fc3w, const float* __restrict__ fc3b,
                            float* __restrict__ out){
  __shared__ float s1[128], s2[128];
  int gi = blockIdx.x, t = threadIdx.x;
  s1[t] = g[gi*128+t];
  __syncthreads();
  float v = fc1b[t];
  for (int i=0;i<128;i++) v += s1[i]*fc1w[i*128+t];
  s2[t] = leaky(v);
  __syncthreads();
  if (t < 64){
    float v2 = fc2b[t];
    for (int i=0;i<128;i++) v2 += s2[i]*fc2w[i*64+t];
    s1[t] = leaky(v2);
  }
  __syncthreads();
  if (t == 0){
    float v3 = fc3b[0];
    for (int i=0;i<64;i++) v3 += s1[i]*fc3w[i];
    out[gi] = v3;
  }
}

extern "C" void kernel_launch(void* const* d_in, const int* in_sizes, int n_in,
                              void* d_out, int out_size, void* d_ws, size_t ws_size,
                              hipStream_t stream) {
  const float* x      = (const float*)d_in[0];
  const int*   ei     = (const int*)  d_in[1];
  const int*   batch  = (const int*)  d_in[2];
  const float* en1_w1 = (const float*)d_in[3];  const float* en1_b1 = (const float*)d_in[4];
  const float* en1_w2 = (const float*)d_in[5];  const float* en1_b2 = (const float*)d_in[6];
  const float* en2_w1 = (const float*)d_in[7];  const float* en2_b1 = (const float*)d_in[8];
  const float* en2_w2 = (const float*)d_in[9];  const float* en2_b2 = (const float*)d_in[10];
  const float* en3_w1 = (const float*)d_in[11]; const float* en3_b1 = (const float*)d_in[12];
  const float* en3_w2 = (const float*)d_in[13]; const float* en3_b2 = (const float*)d_in[14];
  const float* root1  = (const float*)d_in[15]; const float* cb1    = (const float*)d_in[16];
  const float* root2  = (const float*)d_in[17]; const float* cb2    = (const float*)d_in[18];
  const float* root3  = (const float*)d_in[19]; const float* cb3    = (const float*)d_in[20];
  const float* fc1w   = (const float*)d_in[21]; const float* fc1b   = (const float*)d_in[22];
  const float* fc2w   = (const float*)d_in[23]; const float* fc2b   = (const float*)d_in[24];
  const float* fc3w   = (const float*)d_in[25]; const float* fc3b   = (const float*)d_in[26];
  float* out = (float*)d_out;

  const int N = in_sizes[0] / 4;
  const int E = in_sizes[1] / 2;
  const int G = 32;
  const int Epad = (E + 63) & ~63;

  float* ef1  = (float*)d_ws;
  short* ef2b = (short*)(ef1 + (size_t)Epad*64);
  short* ef3b = ef2b + (size_t)Epad*64;
  short* w2p2 = ef3b + (size_t)Epad*64;
  short* w2p3 = w2p2 + 8*4*2*512;            // 32768 shorts
  float* a1   = (float*)(w2p3 + 64*8*2*512); // 524288 shorts
  float* a2   = a1 + (size_t)N*8;
  float* a3   = a2 + (size_t)N*64;
  float* g    = a3 + (size_t)N*128;

  size_t zero_bytes = ((size_t)N*(8+64+128) + (size_t)G*128) * sizeof(float);
  hipMemsetAsync(a1, 0, zero_bytes, stream);

  efeat_all<<<(Epad*64 + 255)/256, 256, 0, stream>>>(
      x, ei, en1_w1, en1_b1, en2_w1, en2_b1, en3_w1, en3_b1,
      ef1, ef2b, ef3b, E, Epad);

  pack_w2_all<<<272, 256, 0, stream>>>(en2_w2, w2p2, en3_w2, w2p3);

  conv1_kernel<<<(E*8 + 255)/256, 256, 0, stream>>>(ef1, x, ei, en1_w2, en1_b2, a1, E);
  node_kernel<4,8><<<(N*8 + 255)/256, 256, 0, stream>>>(a1, x, root1, cb1, N);

  // conv2: 32 edges/block, no ic-split -> Epad/32 blocks
  conv_mfma<8,64,2,8><<<Epad/32, 256, 0, stream>>>(ef2b, a1, ei, w2p2, en2_b2, a2, E);
  node_kernel<8,64><<<(N*64 + 255)/256, 256, 0, stream>>>(a2, a1, root2, cb2, N);

  // conv3: 64 edges/block, 2-way ic-split -> (Epad/64)*2 blocks
  conv_mfma<64,128,4,32><<<(Epad/64)*2, 256, 0, stream>>>(ef3b, a2, ei, w2p3, en3_b2, a3, E);
  node3_pool<<<(N*128 + 255)/256, 256, 0, stream>>>(a3, a2, root3, cb3, batch, g, N);

  head_kernel<<<G, 128, 0, stream>>>(g, fc1w, fc1b, fc2w, fc2b, fc3w, fc3b, out);
}

// Round 5
// 247.465 us; speedup vs baseline: 11.8190x; 1.0269x over previous
//
#include <hip/hip_runtime.h>
#include <hip/hip_bf16.h>

typedef __attribute__((ext_vector_type(8))) short short8;
typedef __attribute__((ext_vector_type(4))) float floatx4;

__device__ __forceinline__ float leaky(float v){ return v > 0.f ? v : 0.1f*v; }
__device__ __forceinline__ void atomAdd(float* p, float v){ unsafeAtomicAdd(p, v); }
__device__ __forceinline__ short f2bf(float f){
  __hip_bfloat16 h = __float2bfloat16(f);
  return *reinterpret_cast<short*>(&h);
}

// Edge features for all 3 nets + fused conv1 (layer-1 message pass).
// Block = 256 threads = 4 edges x 64 j.
__global__ void efeat_conv1(const float* __restrict__ x, const int* __restrict__ ei,
                            const float* __restrict__ w1a, const float* __restrict__ b1a,
                            const float* __restrict__ w1b, const float* __restrict__ b1b,
                            const float* __restrict__ w1c, const float* __restrict__ b1c,
                            const float* __restrict__ c1w2, const float* __restrict__ c1b2,
                            short* __restrict__ ef2b, short* __restrict__ ef3b,
                            float* __restrict__ agg1, int E, int Epad){
  __shared__ float sm[4][64];
  int tid = threadIdx.x;
  int id = blockIdx.x*256 + tid;
  int e = id >> 6, j = id & 63;
  float v1 = 0.f;
  if (e < Epad){
    if (e >= E){ ef2b[id] = 0; ef3b[id] = 0; }
    else {
      int s = ei[e], d = ei[E+e];
      float a0 = x[d*4+1] - x[s*4+1];
      float a1 = x[d*4+2] - x[s*4+2];
      float a2 = x[d*4+3] - x[s*4+3];
      v1 = leaky(a0*w1a[j] + a1*w1a[64+j] + a2*w1a[128+j] + b1a[j]);
      ef2b[id] = f2bf(leaky(a0*w1b[j] + a1*w1b[64+j] + a2*w1b[128+j] + b1b[j]));
      ef3b[id] = f2bf(leaky(a0*w1c[j] + a1*w1c[64+j] + a2*w1c[128+j] + b1c[j]));
    }
  }
  sm[tid >> 6][j] = v1;
  __syncthreads();
  if (tid < 32){
    int le = tid >> 3, o = tid & 7;
    int ge = blockIdx.x*4 + le;
    if (ge < E){
      int s = ei[ge], d = ei[E+ge];
      float z[4];
      #pragma unroll
      for (int i=0;i<4;i++) z[i] = c1b2[i*8+o];
      for (int k=0;k<64;k++){
        float a = sm[le][k];
        #pragma unroll
        for (int i=0;i<4;i++) z[i] += a*c1w2[k*32 + i*8 + o];
      }
      float msg = 0.f;
      #pragma unroll
      for (int i=0;i<4;i++) msg += x[s*4+i]*leaky(z[i]);
      atomAdd(&agg1[d*8+o], msg);
    }
  }
}

// Pack BOTH w2 matrices into bf16 MFMA B-fragment order in one dispatch.
__global__ void pack_w2_all(const float* __restrict__ w2a, short* __restrict__ pa,
                            const float* __restrict__ w2b, short* __restrict__ pb){
  int bid = blockIdx.x;
  const float* w2; short* dst; int IC, OC, cbase;
  if (bid < 16){ w2 = w2a; dst = pa; IC = 8;  OC = 64;  cbase = bid*4; }
  else        { w2 = w2b; dst = pb; IC = 64; OC = 128; cbase = (bid-16)*4; }
  int lane = threadIdx.x & 63;
  int c = cbase + (threadIdx.x >> 6);
  int OT = OC/16;
  int kh = c & 1; int rem = c >> 1; int otg = rem % OT; int i = rem / OT;
  int n = lane & 15, q = lane >> 4;
  short out[8];
  #pragma unroll
  for (int j=0;j<8;j++){
    int k = kh*32 + q*8 + j;
    out[j] = f2bf(w2[(size_t)k*(IC*OC) + i*OC + otg*16 + n]);
  }
  *reinterpret_cast<short8*>(dst + (size_t)c*512 + lane*8) = *reinterpret_cast<short8*>(out);
}

// node update: h = leaky(agg + hin @ root + cb), in-place on agg
template<int IC, int OC>
__global__ void node_kernel(float* __restrict__ h, const float* __restrict__ hin,
                            const float* __restrict__ root, const float* __restrict__ cb, int N){
  int id = blockIdx.x*256 + threadIdx.x;
  if (id >= N*OC) return;
  int n = id / OC, o = id % OC;
  float v = h[id] + cb[o];
  const float* hi = hin + (size_t)n*IC;
  #pragma unroll
  for (int i=0;i<IC;i++) v += hi[i]*root[i*OC+o];
  h[id] = leaky(v);
}

// node3 + pool fused, LDS-tiled: root3 (32KB) + 16 h-rows staged; register pool acc.
__global__ __launch_bounds__(256)
void node3_pool(const float* __restrict__ agg, const float* __restrict__ hin,
                const float* __restrict__ root, const float* __restrict__ cb,
                const int* __restrict__ batch, float* __restrict__ g, int N){
  __shared__ float rootS[64*128];
  __shared__ float hrow[16][64];
  int t = threadIdx.x;
  #pragma unroll
  for (int r=0;r<8;r++){
    int idx = t + r*256;
    reinterpret_cast<float4*>(rootS)[idx] = reinterpret_cast<const float4*>(root)[idx];
  }
  int n0 = blockIdx.x*16;
  {
    int nn = t >> 4, c = (t & 15)*4;
    int n = n0 + nn;
    float4 hv = (n < N) ? *reinterpret_cast<const float4*>(hin + (size_t)n*64 + c)
                        : float4{0.f,0.f,0.f,0.f};
    hrow[nn][c+0]=hv.x; hrow[nn][c+1]=hv.y; hrow[nn][c+2]=hv.z; hrow[nn][c+3]=hv.w;
  }
  __syncthreads();
  int o = t & 127, np = t >> 7;
  float acc = 0.f; int cur = -1;
  for (int rep=0; rep<8; rep++){
    int nl = rep*2 + np; int n = n0 + nl;
    if (n >= N) break;
    int b = batch[n];
    if (b != cur){ if (cur >= 0) atomAdd(&g[cur*128+o], acc); acc = 0.f; cur = b; }
    float v = agg[(size_t)n*128 + o] + cb[o];
    #pragma unroll 16
    for (int i=0;i<64;i++) v += hrow[nl][i]*rootS[i*128+o];
    acc += leaky(v);
  }
  if (cur >= 0) atomAdd(&g[cur*128+o], acc);
}

// Generalized MFMA NNConv with software-pipelined B-fragment loads.
template<int IC, int OC, int MB, int ICB>
__global__ __launch_bounds__(256)
void conv_mfma(const short* __restrict__ efb, const float* __restrict__ h,
               const int* __restrict__ ei, const short* __restrict__ w2p,
               const float* __restrict__ b2, float* __restrict__ agg, int E){
  constexpr int ME   = MB*16;
  constexpr int OT   = OC/16;
  constexpr int WOT  = OT/4;
  constexpr int NSPL = IC/ICB;
  __shared__ float hsT[ICB][ME];
  __shared__ int sdst[ME];
  int tid = threadIdx.x;
  int bi = blockIdx.x;
  int eb = (bi / NSPL) * ME;
  int i0 = (bi % NSPL) * ICB;

  { // stage h[src, i0:i0+ICB] transposed into hsT[i_local][e]
    int e = tid % ME;
    int ge = eb + e;
    bool valid = ge < E;
    int src = valid ? ei[ge] : 0;
    constexpr int CH  = 256/ME;
    constexpr int IPC = ICB/CH;
    int c = tid / ME;
    const float* hp = h + (size_t)src*IC + i0 + c*IPC;
    if constexpr (IPC == 8){
      #pragma unroll
      for (int half=0; half<2; half++){
        float4 hv = valid ? reinterpret_cast<const float4*>(hp)[half]
                          : float4{0.f,0.f,0.f,0.f};
        hsT[c*IPC + half*4 + 0][e] = hv.x;
        hsT[c*IPC + half*4 + 1][e] = hv.y;
        hsT[c*IPC + half*4 + 2][e] = hv.z;
        hsT[c*IPC + half*4 + 3][e] = hv.w;
      }
    } else {
      #pragma unroll
      for (int j=0;j<IPC;j++)
        hsT[c*IPC + j][e] = valid ? hp[j] : 0.f;
    }
    if (tid < ME) sdst[tid] = (eb + tid < E) ? ei[E + eb + tid] : -1;
  }
  __syncthreads();

  int lane = tid & 63;
  int wv = tid >> 6;
  int n = lane & 15, quad = lane >> 4;
  int o0 = wv * (OC/4);

  short8 A[MB][2];
  #pragma unroll
  for (int m=0;m<MB;m++)
    #pragma unroll
    for (int kh=0;kh<2;kh++)
      A[m][kh] = *reinterpret_cast<const short8*>(efb + (size_t)(eb + m*16 + n)*64 + kh*32 + quad*8);

  float msg[MB][WOT][4];
  #pragma unroll
  for (int m=0;m<MB;m++)
    #pragma unroll
    for (int t=0;t<WOT;t++)
      #pragma unroll
      for (int r=0;r<4;r++) msg[m][t][r] = 0.f;

  auto loadB = [&](int i, short8 (&Bt)[WOT][2], float (&bzt)[WOT]){
    int ig = i0 + i;
    #pragma unroll
    for (int t=0;t<WOT;t++){
      int otg = (o0 >> 4) + t;
      #pragma unroll
      for (int kh=0;kh<2;kh++)
        Bt[t][kh] = *reinterpret_cast<const short8*>(w2p + ((size_t)((ig*OT + otg)*2 + kh) << 9) + lane*8);
      bzt[t] = b2[ig*OC + o0 + t*16 + n];
    }
  };
  auto compute = [&](int i, short8 (&Bt)[WOT][2], float (&bzt)[WOT]){
    #pragma unroll
    for (int m=0;m<MB;m++){
      float4 hv = *reinterpret_cast<const float4*>(&hsT[i][m*16 + quad*4]);
      #pragma unroll
      for (int t=0;t<WOT;t++){
        floatx4 z = {bzt[t], bzt[t], bzt[t], bzt[t]};
        z = __builtin_amdgcn_mfma_f32_16x16x32_bf16(A[m][0], Bt[t][0], z, 0, 0, 0);
        z = __builtin_amdgcn_mfma_f32_16x16x32_bf16(A[m][1], Bt[t][1], z, 0, 0, 0);
        float l0 = fmaxf(z[0], 0.1f*z[0]);
        float l1 = fmaxf(z[1], 0.1f*z[1]);
        float l2 = fmaxf(z[2], 0.1f*z[2]);
        float l3 = fmaxf(z[3], 0.1f*z[3]);
        msg[m][t][0] += hv.x*l0;
        msg[m][t][1] += hv.y*l1;
        msg[m][t][2] += hv.z*l2;
        msg[m][t][3] += hv.w*l3;
      }
    }
  };

  short8 Bc[WOT][2], Bn[WOT][2];
  float bzc[WOT], bzn[WOT];
  loadB(0, Bc, bzc);
  for (int i=0;i<ICB-1;i++){
    loadB(i+1, Bn, bzn);      // in flight during compute(i)
    compute(i, Bc, bzc);
    #pragma unroll
    for (int t=0;t<WOT;t++){
      Bc[t][0] = Bn[t][0]; Bc[t][1] = Bn[t][1]; bzc[t] = bzn[t];
    }
  }
  compute(ICB-1, Bc, bzc);

  #pragma unroll
  for (int m=0;m<MB;m++){
    #pragma unroll
    for (int r=0;r<4;r++){
      int d = sdst[m*16 + quad*4 + r];
      if (d >= 0){
        #pragma unroll
        for (int t=0;t<WOT;t++)
          atomAdd(&agg[(size_t)d*OC + o0 + t*16 + n], msg[m][t][r]);
      }
    }
  }
}

// readout MLP: one block per graph
__global__ void head_kernel(const float* __restrict__ g,
                            const float* __restrict__ fc1w, const float* __restrict__ fc1b,
                            const float* __restrict__ fc2w, const float* __restrict__ fc2b,
                            const float* __restrict__ fc3w, const float* __restrict__ fc3b,
                            float* __restrict__ out){
  __shared__ float s1[128], s2[128];
  int gi = blockIdx.x, t = threadIdx.x;
  s1[t] = g[gi*128+t];
  __syncthreads();
  float v = fc1b[t];
  for (int i=0;i<128;i++) v += s1[i]*fc1w[i*128+t];
  s2[t] = leaky(v);
  __syncthreads();
  if (t < 64){
    float v2 = fc2b[t];
    for (int i=0;i<128;i++) v2 += s2[i]*fc2w[i*64+t];
    s1[t] = leaky(v2);
  }
  __syncthreads();
  if (t == 0){
    float v3 = fc3b[0];
    for (int i=0;i<64;i++) v3 += s1[i]*fc3w[i];
    out[gi] = v3;
  }
}

extern "C" void kernel_launch(void* const* d_in, const int* in_sizes, int n_in,
                              void* d_out, int out_size, void* d_ws, size_t ws_size,
                              hipStream_t stream) {
  const float* x      = (const float*)d_in[0];
  const int*   ei     = (const int*)  d_in[1];
  const int*   batch  = (const int*)  d_in[2];
  const float* en1_w1 = (const float*)d_in[3];  const float* en1_b1 = (const float*)d_in[4];
  const float* en1_w2 = (const float*)d_in[5];  const float* en1_b2 = (const float*)d_in[6];
  const float* en2_w1 = (const float*)d_in[7];  const float* en2_b1 = (const float*)d_in[8];
  const float* en2_w2 = (const float*)d_in[9];  const float* en2_b2 = (const float*)d_in[10];
  const float* en3_w1 = (const float*)d_in[11]; const float* en3_b1 = (const float*)d_in[12];
  const float* en3_w2 = (const float*)d_in[13]; const float* en3_b2 = (const float*)d_in[14];
  const float* root1  = (const float*)d_in[15]; const float* cb1    = (const float*)d_in[16];
  const float* root2  = (const float*)d_in[17]; const float* cb2    = (const float*)d_in[18];
  const float* root3  = (const float*)d_in[19]; const float* cb3    = (const float*)d_in[20];
  const float* fc1w   = (const float*)d_in[21]; const float* fc1b   = (const float*)d_in[22];
  const float* fc2w   = (const float*)d_in[23]; const float* fc2b   = (const float*)d_in[24];
  const float* fc3w   = (const float*)d_in[25]; const float* fc3b   = (const float*)d_in[26];
  float* out = (float*)d_out;

  const int N = in_sizes[0] / 4;
  const int E = in_sizes[1] / 2;
  const int G = 32;
  const int Epad = (E + 63) & ~63;

  short* ef2b = (short*)d_ws;
  short* ef3b = ef2b + (size_t)Epad*64;
  short* w2p2 = ef3b + (size_t)Epad*64;
  short* w2p3 = w2p2 + 8*4*2*512;            // 32768 shorts
  float* a1   = (float*)(w2p3 + 64*8*2*512); // 524288 shorts
  float* a2   = a1 + (size_t)N*8;
  float* a3   = a2 + (size_t)N*64;
  float* g    = a3 + (size_t)N*128;

  size_t zero_bytes = ((size_t)N*(8+64+128) + (size_t)G*128) * sizeof(float);
  hipMemsetAsync(a1, 0, zero_bytes, stream);

  efeat_conv1<<<Epad/4, 256, 0, stream>>>(
      x, ei, en1_w1, en1_b1, en2_w1, en2_b1, en3_w1, en3_b1,
      en1_w2, en1_b2, ef2b, ef3b, a1, E, Epad);

  pack_w2_all<<<272, 256, 0, stream>>>(en2_w2, w2p2, en3_w2, w2p3);

  node_kernel<4,8><<<(N*8 + 255)/256, 256, 0, stream>>>(a1, x, root1, cb1, N);

  conv_mfma<8,64,2,8><<<Epad/32, 256, 0, stream>>>(ef2b, a1, ei, w2p2, en2_b2, a2, E);
  node_kernel<8,64><<<(N*64 + 255)/256, 256, 0, stream>>>(a2, a1, root2, cb2, N);

  conv_mfma<64,128,4,32><<<(Epad/64)*2, 256, 0, stream>>>(ef3b, a2, ei, w2p3, en3_b2, a3, E);
  node3_pool<<<(N + 15)/16, 256, 0, stream>>>(a3, a2, root3, cb3, batch, g, N);

  head_kernel<<<G, 128, 0, stream>>>(g, fc1w, fc1b, fc2w, fc2b, fc3w, fc3b, out);
}